// Round 6
// baseline (81.355 us; speedup 1.0000x reference)
//
#include <hip/hip_runtime.h>

#define S_LEN 1024
#define D_DIM 128
#define NH    32
#define NKV   8
#define NB    2

typedef __bf16 bf16x8 __attribute__((ext_vector_type(8)));
typedef float  f32x16 __attribute__((ext_vector_type(16)));
typedef unsigned short u16x8 __attribute__((ext_vector_type(8)));
typedef unsigned int   u32x4 __attribute__((ext_vector_type(4)));

__device__ __forceinline__ unsigned short f2bf(float f) {
    unsigned int u = __float_as_uint(f);
    u += 0x7fffu + ((u >> 16) & 1u);      // RNE
    return (unsigned short)(u >> 16);
}

// async global->LDS, 16B per lane; LDS dest is wave-uniform base + lane*16
__device__ __forceinline__ void gld_lds16(const unsigned short* g, unsigned short* l) {
    __builtin_amdgcn_global_load_lds(
        (const __attribute__((address_space(1))) unsigned int*)(g),
        (__attribute__((address_space(3))) unsigned int*)(l), 16, 0, 0);
}

// ---- fused prep: RoPE K (blocks [0,4096)) + V transpose (blocks [4096,4352))
__global__ __launch_bounds__(256) void prep_kv_kernel(
    const float* __restrict__ k, const float* __restrict__ cosb,
    const float* __restrict__ sinb, const float* __restrict__ v,
    unsigned short* __restrict__ Kr, unsigned short* __restrict__ Vt)
{
    const int tid = threadIdx.x;
    __shared__ __align__(16) unsigned short tile[64][132];
    if (blockIdx.x < 4096) {
        int gid = blockIdx.x * 256 + tid;
        int row = gid >> 6;            // (b*S + s)*NKV + hk
        int j   = gid & 63;
        int hk = row & (NKV - 1);
        int bs = row >> 3;
        int s  = bs & (S_LEN - 1);
        int b  = bs >> 10;
        const float* kp = k + (size_t)row * D_DIM;
        float x0 = kp[j];
        float x1 = kp[j + 64];
        float c  = cosb[s * D_DIM + j];
        float sn = sinb[s * D_DIM + j];
        size_t orow = ((size_t)(b * NKV + hk) * S_LEN + s) * D_DIM;
        Kr[orow + j]      = f2bf(x0 * c - x1 * sn);
        Kr[orow + j + 64] = f2bf(x1 * c + x0 * sn);
    } else {
        int blk   = blockIdx.x - 4096;     // (b, hk, stile)
        int stile = blk & 15;
        int hk    = (blk >> 4) & (NKV - 1);
        int b     = blk >> 7;
#pragma unroll
        for (int i = 0; i < 8; i++) {
            int e    = i * 256 + tid;
            int srow = e >> 5;
            int dq   = (e & 31) * 4;
            const float* vp = v + (((size_t)(b * S_LEN + stile * 64 + srow) * NKV + hk) * D_DIM + dq);
            float4 val = *(const float4*)vp;
            tile[srow][dq + 0] = f2bf(val.x);
            tile[srow][dq + 1] = f2bf(val.y);
            tile[srow][dq + 2] = f2bf(val.z);
            tile[srow][dq + 3] = f2bf(val.w);
        }
        __syncthreads();
        size_t head = (size_t)(b * NKV + hk) * D_DIM * S_LEN;
#pragma unroll
        for (int i = 0; i < 4; i++) {
            int g  = i * 256 + tid;
            int d  = g >> 3;
            int c8 = g & 7;
            int s0 = c8 * 8;
            u16x8 pk;
#pragma unroll
            for (int jj = 0; jj < 8; jj++) pk[jj] = tile[s0 + jj][d];
            *(u16x8*)(Vt + head + (size_t)d * S_LEN + stile * 64 + s0) = pk;
        }
    }
}

// ---------------- fused causal GQA flash attention --------------------------
// 4 waves x 32 q-rows (QBLK=128), KVBLK=64, 32x32x16 MFMA, swapped QK^T,
// in-register softmax, inline Q-RoPE, pair-in-block (18 kv-iters uniform),
// triple-buffered K/V via global_load_lds with counted vmcnt across raw barriers.
__global__ __launch_bounds__(256) void attn_kernel(
    const float* __restrict__ qraw,
    const unsigned short* __restrict__ Kr,
    const unsigned short* __restrict__ Vt,
    const float* __restrict__ cosb, const float* __restrict__ sinb,
    const float* __restrict__ scale_ptr,
    float* __restrict__ out)
{
    const int bid  = blockIdx.x;       // 0..255
    const int pr   = bid & 3;          // pair id: passes do tiles (7-pr, pr)
    const int head = bid >> 2;         // 0..63
    const int h    = head & 31;
    const int b    = head >> 5;
    const int hk   = h >> 2;           // GQA

    const int tid  = threadIdx.x;
    const int w    = tid >> 6;         // wave 0..3
    const int lane = tid & 63;
    const int ln   = lane & 31;
    const int hi   = lane >> 5;

    const float sc = *scale_ptr * 1.44269504088896f;   // fold log2(e): exp2 domain

    __shared__ __align__(16) unsigned short Kt[3][64 * 128];   // [k][d], swizzled
    __shared__ __align__(16) unsigned short Vs[3][128 * 64];   // [d][k], swizzled

    const unsigned short* khead = Kr + (size_t)(b * NKV + hk) * S_LEN * D_DIM;
    const unsigned short* vhead = Vt + (size_t)(b * NKV + hk) * D_DIM * S_LEN;

    // staging geometry: wave w -> K rows [16w,16w+16), V d-rows [32w,32w+32)
    const int krow = lane >> 4;        // 0..3
    const int kcc  = lane & 15;
    const int vrw  = lane >> 3;        // 0..7
    const int vcc  = lane & 7;

    auto stage = [&](int u, int buf) {     // 8 gld_lds16 per wave per tile
        const unsigned short* kt = khead + (size_t)u * 64 * D_DIM;
#pragma unroll
        for (int n = 0; n < 4; n++) {
            int row = w * 16 + n * 4 + krow;
            int cc  = kcc ^ (row & 7);                       // pre-inverse-swizzled src
            gld_lds16(kt + (size_t)row * D_DIM + cc * 8, &Kt[buf][(w * 16 + n * 4) * 128]);
        }
        const unsigned short* vt = vhead + (size_t)u * 64;
#pragma unroll
        for (int n = 0; n < 4; n++) {
            int d  = w * 32 + n * 8 + vrw;
            int cc = vcc ^ (d & 7);
            gld_lds16(vt + (size_t)d * S_LEN + cc * 8, &Vs[buf][(w * 32 + n * 8) * 64]);
        }
    };

#pragma unroll 1
    for (int pass = 0; pass < 2; ++pass) {
        const int qt = pass ? pr : (7 - pr);   // q-tile of 128 rows
        const int U  = 2 * qt + 2;             // kv tiles 0..U-1
        const int q0 = qt * 128 + w * 32;      // wave's first q-row
        const int qg = q0 + ln;                // lane's q-row

        // ---- inline RoPE Q -> fragments (lane ln holds row qg) ----
        // element d = 16dd + 8hi + j; pairs (dd, dd+4) share loads
        const float* qrowf = qraw + (((size_t)(b * S_LEN + qg)) * NH + h) * D_DIM;
        const float* ct = cosb + (size_t)qg * D_DIM;
        const float* st_ = sinb + (size_t)qg * D_DIM;
        bf16x8 qf[8];
#pragma unroll
        for (int dd = 0; dd < 4; dd++) {
            int b0 = dd * 16 + hi * 8;
            int b1 = b0 + 64;
            float4 x0a = *(const float4*)(qrowf + b0), x0b = *(const float4*)(qrowf + b0 + 4);
            float4 x1a = *(const float4*)(qrowf + b1), x1b = *(const float4*)(qrowf + b1 + 4);
            float4 c0a = *(const float4*)(ct + b0),  c0b = *(const float4*)(ct + b0 + 4);
            float4 c1a = *(const float4*)(ct + b1),  c1b = *(const float4*)(ct + b1 + 4);
            float4 s0a = *(const float4*)(st_ + b0), s0b = *(const float4*)(st_ + b0 + 4);
            float4 s1a = *(const float4*)(st_ + b1), s1b = *(const float4*)(st_ + b1 + 4);
            u16x8 lo, hi8;
#pragma unroll
            for (int j = 0; j < 4; j++) {
                float xl0 = ((const float*)&x0a)[j], xh0 = ((const float*)&x1a)[j];
                lo[j]  = f2bf((xl0 * ((const float*)&c0a)[j] - xh0 * ((const float*)&s0a)[j]) * sc);
                hi8[j] = f2bf((xh0 * ((const float*)&c1a)[j] + xl0 * ((const float*)&s1a)[j]) * sc);
                float xl1 = ((const float*)&x0b)[j], xh1 = ((const float*)&x1b)[j];
                lo[j + 4]  = f2bf((xl1 * ((const float*)&c0b)[j] - xh1 * ((const float*)&s0b)[j]) * sc);
                hi8[j + 4] = f2bf((xh1 * ((const float*)&c1b)[j] + xl1 * ((const float*)&s1b)[j]) * sc);
            }
            qf[dd]     = __builtin_bit_cast(bf16x8, lo);
            qf[dd + 4] = __builtin_bit_cast(bf16x8, hi8);
        }

        f32x16 o[4];                   // O[q][d]: col d = 32dt+ln, row q = crow(r,hi)
#pragma unroll
        for (int dt = 0; dt < 4; dt++)
#pragma unroll
            for (int r = 0; r < 16; r++) o[dt][r] = 0.f;
        float m_run = -1e30f, lsum = 0.f;

        if (pass) __builtin_amdgcn_s_barrier();    // all waves done with pass-0 buffers
        stage(0, 0);
        stage(1, 1);

#pragma unroll 1
        for (int u = 0; u < U; ++u) {
            const int cur = u % 3;
            // counted wait: tile u landed; tile u+1's 8 loads may stay in flight
            if (u + 1 < U) asm volatile("s_waitcnt vmcnt(8)" ::: "memory");
            else           asm volatile("s_waitcnt vmcnt(0)" ::: "memory");
            __builtin_amdgcn_s_barrier();
            __builtin_amdgcn_sched_barrier(0);
            if (u + 2 < U) stage(u + 2, (u + 2) % 3);   // depth-2 prefetch

            if (64 * u <= q0 + 31) {               // wave has unmasked elements
                const bool act1 = (64 * u + 32 <= q0 + 31);

                // ---- S^T = K Q^T (swapped): st[s] col q=ln, row k=32s+crow(r,hi)
                f32x16 st[2];
#pragma unroll
                for (int r = 0; r < 16; r++) { st[0][r] = 0.f; st[1][r] = 0.f; }
                __builtin_amdgcn_s_setprio(1);
#pragma unroll
                for (int s = 0; s < 2; s++) {
                    if (s == 0 || act1) {
#pragma unroll
                        for (int dd = 0; dd < 8; dd++) {
                            int row = s * 32 + ln;
                            int c   = (2 * dd + hi) ^ (row & 7);
                            bf16x8 kf = *(const bf16x8*)(&Kt[cur][row * 128 + c * 8]);
                            st[s] = __builtin_amdgcn_mfma_f32_32x32x16_bf16(kf, qf[dd], st[s], 0, 0, 0);
                        }
                    }
                }
                __builtin_amdgcn_s_setprio(0);

                // ---- causal mask (diagonal band only) ----
                if (64 * u + 63 > q0) {
#pragma unroll
                    for (int s = 0; s < 2; s++)
#pragma unroll
                        for (int r = 0; r < 16; r++) {
                            int kg = 64 * u + 32 * s + (r & 3) + 8 * (r >> 2) + 4 * hi;
                            if (kg > qg) st[s][r] = -1e30f;
                        }
                }

                // ---- in-register online softmax (log2 domain) ----
                float mx = -1e30f;
#pragma unroll
                for (int r = 0; r < 16; r++) mx = fmaxf(mx, st[0][r]);
                if (act1) {
#pragma unroll
                    for (int r = 0; r < 16; r++) mx = fmaxf(mx, st[1][r]);
                }
                float pm = fmaxf(mx, __shfl_xor(mx, 32));   // full 64-k row max

                if (__any(pm > m_run + 8.f)) {     // T13 defer-max
                    float mnew = fmaxf(m_run, pm);
                    float ps   = exp2f(m_run - mnew);
                    m_run = mnew;
                    lsum *= ps;
#pragma unroll
                    for (int r = 0; r < 16; r++) {
                        float psr = __shfl(ps, (r & 3) + 8 * (r >> 2) + 4 * hi);
#pragma unroll
                        for (int dt = 0; dt < 4; dt++) o[dt][r] *= psr;
                    }
                }
                float ls = 0.f;
#pragma unroll
                for (int r = 0; r < 16; r++) {
                    float p = exp2f(st[0][r] - m_run);
                    st[0][r] = p; ls += p;
                }
                if (act1) {
#pragma unroll
                    for (int r = 0; r < 16; r++) {
                        float p = exp2f(st[1][r] - m_run);
                        st[1][r] = p; ls += p;
                    }
                }
                lsum += ls + __shfl_xor(ls, 32);

                // ---- P->A-frags lane-local + O += P V ----
                // step ks: rows r = 8*(ks&1)+[0,8) of st[ks>>1];
                // element jj <-> k = 16ks + 8*(jj>>2) + 4hi + (jj&3)  (pairing g)
                const char* vbase = (const char*)&Vs[cur][0];
                __builtin_amdgcn_s_setprio(1);
#pragma unroll
                for (int ks = 0; ks < 4; ks++) {
                    if (ks < 2 || act1) {
                        const f32x16& sv = st[ks >> 1];
                        const int g = (ks & 1) * 8;
                        unsigned int d0 = (unsigned)f2bf(sv[g + 0]) | ((unsigned)f2bf(sv[g + 1]) << 16);
                        unsigned int d1 = (unsigned)f2bf(sv[g + 2]) | ((unsigned)f2bf(sv[g + 3]) << 16);
                        unsigned int d2 = (unsigned)f2bf(sv[g + 4]) | ((unsigned)f2bf(sv[g + 5]) << 16);
                        unsigned int d3 = (unsigned)f2bf(sv[g + 6]) | ((unsigned)f2bf(sv[g + 7]) << 16);
                        u32x4 paw = {d0, d1, d2, d3};
                        bf16x8 pa = __builtin_bit_cast(bf16x8, paw);
#pragma unroll
                        for (int dt = 0; dt < 4; dt++) {
                            int d = dt * 32 + ln;
                            const char* vrow = vbase + d * 128;
                            int x = d & 7;
                            uint2 vlo = *(const uint2*)(vrow + (((2 * ks)     ^ x) * 16) + hi * 8);
                            uint2 vhi = *(const uint2*)(vrow + (((2 * ks + 1) ^ x) * 16) + hi * 8);
                            u32x4 vw = {vlo.x, vlo.y, vhi.x, vhi.y};
                            bf16x8 vf = __builtin_bit_cast(bf16x8, vw);
                            o[dt] = __builtin_amdgcn_mfma_f32_32x32x16_bf16(pa, vf, o[dt], 0, 0, 0);
                        }
                    }
                }
                __builtin_amdgcn_s_setprio(0);
            }
        }

        // ---- epilogue: normalize, store f32 [B,S,H,D] ----
        float rcp = 1.0f / lsum;               // owner lane ln holds q-row q0+ln
        float* ob = out + ((size_t)(b * S_LEN + q0) * NH + h) * D_DIM;
#pragma unroll
        for (int r = 0; r < 16; r++) {
            int qo = (r & 3) + 8 * (r >> 2) + 4 * hi;
            float invr = __shfl(rcp, qo);
#pragma unroll
            for (int dt = 0; dt < 4; dt++)
                ob[(size_t)qo * NH * D_DIM + dt * 32 + ln] = o[dt][r] * invr;
        }
    }
}

extern "C" void kernel_launch(void* const* d_in, const int* in_sizes, int n_in,
                              void* d_out, int out_size, void* d_ws, size_t ws_size,
                              hipStream_t stream) {
    const float* q    = (const float*)d_in[0];
    const float* k    = (const float*)d_in[1];
    const float* v    = (const float*)d_in[2];
    const float* cosb = (const float*)d_in[3];
    const float* sinb = (const float*)d_in[4];
    // d_in[5] = attention_mask: exactly causal -> implemented analytically
    const float* scale = (const float*)d_in[6];
    float* out = (float*)d_out;

    unsigned short* Kr = (unsigned short*)d_ws;
    unsigned short* Vt = Kr + (size_t)NB * NKV * S_LEN * D_DIM;

    prep_kv_kernel<<<4096 + 256, 256, 0, stream>>>(k, cosb, sinb, v, Kr, Vt);
    attn_kernel<<<256, 256, 0, stream>>>(q, Kr, Vt, cosb, sinb, scale, out);
}

// Round 7
// 75.916 us; speedup vs baseline: 1.0716x; 1.0716x over previous
//
#include <hip/hip_runtime.h>

#define S_LEN 1024
#define D_DIM 128
#define NH    32
#define NKV   8
#define NB    2

typedef __bf16 bf16x8 __attribute__((ext_vector_type(8)));
typedef float  f32x16 __attribute__((ext_vector_type(16)));
typedef unsigned short u16x8 __attribute__((ext_vector_type(8)));
typedef unsigned int   u32x4 __attribute__((ext_vector_type(4)));

__device__ __forceinline__ unsigned short f2bf(float f) {
    unsigned int u = __float_as_uint(f);
    u += 0x7fffu + ((u >> 16) & 1u);      // RNE
    return (unsigned short)(u >> 16);
}

// async global->LDS, 16B per lane; LDS dest is wave-uniform base + lane*16
__device__ __forceinline__ void gld_lds16(const unsigned short* g, unsigned short* l) {
    __builtin_amdgcn_global_load_lds(
        (const __attribute__((address_space(1))) unsigned int*)(g),
        (__attribute__((address_space(3))) unsigned int*)(l), 16, 0, 0);
}

// ---- fused prep: RoPE Q [0,16384) | RoPE K [16384,20480) | V^T [20480,20736)
__global__ __launch_bounds__(256) void prep_kernel(
    const float* __restrict__ q, const float* __restrict__ k,
    const float* __restrict__ v, const float* __restrict__ cosb,
    const float* __restrict__ sinb, const float* __restrict__ scale_ptr,
    unsigned short* __restrict__ Qr, unsigned short* __restrict__ Kr,
    unsigned short* __restrict__ Vt)
{
    const int bx  = blockIdx.x;
    const int tid = threadIdx.x;
    __shared__ __align__(16) unsigned short tile[64][132];
    if (bx < 16384) {
        // ---- RoPE Q (scale*log2e folded): q[B,S,H,D] f32 -> Qr[B,H,S,D] bf16
        const float sc = *scale_ptr * 1.44269504088896f;   // exp2 domain
        int gid = bx * 256 + tid;
        int row = gid >> 6;            // (b*S + s)*NH + h
        int j   = gid & 63;
        int h  = row & (NH - 1);
        int bs = row >> 5;             // b*S + s
        int s  = bs & (S_LEN - 1);
        int b  = bs >> 10;
        const float* qp = q + (size_t)row * D_DIM;
        float x0 = qp[j];
        float x1 = qp[j + 64];
        float c  = cosb[s * D_DIM + j];
        float sn = sinb[s * D_DIM + j];
        size_t orow = ((size_t)(b * NH + h) * S_LEN + s) * D_DIM;
        Qr[orow + j]      = f2bf((x0 * c - x1 * sn) * sc);
        Qr[orow + j + 64] = f2bf((x1 * c + x0 * sn) * sc);
    } else if (bx < 20480) {
        // ---- RoPE K: k[B,S,HKV,D] f32 -> Kr[B,HKV,S,D] bf16 ----
        int gid = (bx - 16384) * 256 + tid;
        int row = gid >> 6;            // (b*S + s)*NKV + hk
        int j   = gid & 63;
        int hk = row & (NKV - 1);
        int bs = row >> 3;
        int s  = bs & (S_LEN - 1);
        int b  = bs >> 10;
        const float* kp = k + (size_t)row * D_DIM;
        float x0 = kp[j];
        float x1 = kp[j + 64];
        float c  = cosb[s * D_DIM + j];
        float sn = sinb[s * D_DIM + j];
        size_t orow = ((size_t)(b * NKV + hk) * S_LEN + s) * D_DIM;
        Kr[orow + j]      = f2bf(x0 * c - x1 * sn);
        Kr[orow + j + 64] = f2bf(x1 * c + x0 * sn);
    } else {
        // ---- V transpose: v[B,S,HKV,D] f32 -> Vt[B,HKV,D,S] bf16 ----
        int blk   = bx - 20480;        // (b, hk, stile)
        int stile = blk & 15;
        int hk    = (blk >> 4) & (NKV - 1);
        int b     = blk >> 7;
#pragma unroll
        for (int i = 0; i < 8; i++) {
            int e    = i * 256 + tid;
            int srow = e >> 5;
            int dq   = (e & 31) * 4;
            const float* vp = v + (((size_t)(b * S_LEN + stile * 64 + srow) * NKV + hk) * D_DIM + dq);
            float4 val = *(const float4*)vp;
            tile[srow][dq + 0] = f2bf(val.x);
            tile[srow][dq + 1] = f2bf(val.y);
            tile[srow][dq + 2] = f2bf(val.z);
            tile[srow][dq + 3] = f2bf(val.w);
        }
        __syncthreads();
        size_t head = (size_t)(b * NKV + hk) * D_DIM * S_LEN;
#pragma unroll
        for (int i = 0; i < 4; i++) {
            int g  = i * 256 + tid;
            int d  = g >> 3;
            int c8 = g & 7;
            int s0 = c8 * 8;
            u16x8 pk;
#pragma unroll
            for (int jj = 0; jj < 8; jj++) pk[jj] = tile[s0 + jj][d];
            *(u16x8*)(Vt + head + (size_t)d * S_LEN + stile * 64 + s0) = pk;
        }
    }
}

// ---------------- fused causal GQA flash attention --------------------------
// 4 waves x 32 q-rows (QBLK=128), KVBLK=64, 32x32x16 MFMA, swapped QK^T,
// in-register softmax, lane-local P->A frags, dbuf K/V via global_load_lds,
// 1 barrier/tile. Grid 512 (2 blocks/CU), big-U blocks dispatched first.
__global__ __launch_bounds__(256) void attn_kernel(
    const unsigned short* __restrict__ Qr,
    const unsigned short* __restrict__ Kr,
    const unsigned short* __restrict__ Vt,
    float* __restrict__ out)
{
    const int bid  = blockIdx.x;       // 0..511
    const int qt   = 7 - (bid >> 6);   // q-tile (128 rows); big tiles first
    const int head = bid & 63;
    const int h    = head & 31;
    const int b    = head >> 5;
    const int hk   = h >> 2;           // GQA

    const int tid  = threadIdx.x;
    const int w    = tid >> 6;         // wave 0..3
    const int lane = tid & 63;
    const int ln   = lane & 31;
    const int hi   = lane >> 5;

    __shared__ __align__(16) unsigned short Kt[2][64 * 128];   // [k][d], swizzled
    __shared__ __align__(16) unsigned short Vs[2][128 * 64];   // [d][k], swizzled

    const int q0 = qt * 128 + w * 32;  // wave's first q-row
    const int qg = q0 + ln;            // lane's q-row (softmax owner)
    const int U  = 2 * qt + 2;         // kv tiles

    const unsigned short* khead = Kr + (size_t)(b * NKV + hk) * S_LEN * D_DIM;
    const unsigned short* vhead = Vt + (size_t)(b * NKV + hk) * D_DIM * S_LEN;

    // staging geometry: wave w -> K rows [16w,16w+16), V d-rows [32w,32w+32)
    const int krow = lane >> 4;        // 0..3
    const int kcc  = lane & 15;
    const int vrw  = lane >> 3;        // 0..7
    const int vcc  = lane & 7;

    auto stage = [&](int u, int buf) {     // 8 gld_lds16 per wave per tile
        const unsigned short* kt = khead + (size_t)u * 64 * D_DIM;
#pragma unroll
        for (int n = 0; n < 4; n++) {
            int row = w * 16 + n * 4 + krow;
            int cc  = kcc ^ (row & 7);                       // pre-inverse-swizzled src
            gld_lds16(kt + (size_t)row * D_DIM + cc * 8, &Kt[buf][(w * 16 + n * 4) * 128]);
        }
        const unsigned short* vt = vhead + (size_t)u * 64;
#pragma unroll
        for (int n = 0; n < 4; n++) {
            int d  = w * 32 + n * 8 + vrw;
            int cc = vcc ^ (d & 7);
            gld_lds16(vt + (size_t)d * S_LEN + cc * 8, &Vs[buf][(w * 32 + n * 8) * 64]);
        }
    };

    // Q fragments: lane (ln,hi) holds row qg, elements d = 16dd + 8hi + [0,8)
    const unsigned short* qrow =
        Qr + ((size_t)(b * NH + h) * S_LEN + qg) * D_DIM + hi * 8;
    bf16x8 qf[8];
#pragma unroll
    for (int dd = 0; dd < 8; dd++)
        qf[dd] = *(const bf16x8*)(qrow + dd * 16);

    f32x16 o[4];                       // O[q][d]: col d = 32dt+ln, row q = crow(r,hi)
#pragma unroll
    for (int dt = 0; dt < 4; dt++)
#pragma unroll
        for (int r = 0; r < 16; r++) o[dt][r] = 0.f;
    float m_run = -1e30f, lsum = 0.f;

    stage(0, 0);

#pragma unroll 1
    for (int u = 0; u < U; ++u) {
        const int cur = u & 1;
        __syncthreads();                       // stage(u) complete; prev readers done
        if (u + 1 < U) stage(u + 1, cur ^ 1);  // flies during compute

        if (64 * u <= q0 + 31) {               // wave has unmasked elements
            const bool act1 = (64 * u + 32 <= q0 + 31);

            // ---- S^T = K Q^T (swapped): st[s] col q=ln, row k=32s+crow(r,hi)
            f32x16 st[2];
#pragma unroll
            for (int r = 0; r < 16; r++) { st[0][r] = 0.f; st[1][r] = 0.f; }
            __builtin_amdgcn_s_setprio(1);
#pragma unroll
            for (int s = 0; s < 2; s++) {
                if (s == 0 || act1) {
#pragma unroll
                    for (int dd = 0; dd < 8; dd++) {
                        int row = s * 32 + ln;
                        int c   = (2 * dd + hi) ^ (row & 7);
                        bf16x8 kf = *(const bf16x8*)(&Kt[cur][row * 128 + c * 8]);
                        st[s] = __builtin_amdgcn_mfma_f32_32x32x16_bf16(kf, qf[dd], st[s], 0, 0, 0);
                    }
                }
            }
            __builtin_amdgcn_s_setprio(0);

            // ---- causal mask (diagonal band only) ----
            if (64 * u + 63 > q0) {
#pragma unroll
                for (int s = 0; s < 2; s++)
#pragma unroll
                    for (int r = 0; r < 16; r++) {
                        int kg = 64 * u + 32 * s + (r & 3) + 8 * (r >> 2) + 4 * hi;
                        if (kg > qg) st[s][r] = -1e30f;
                    }
            }

            // ---- in-register online softmax (log2 domain) ----
            float mx = -1e30f;
#pragma unroll
            for (int r = 0; r < 16; r++) mx = fmaxf(mx, st[0][r]);
            if (act1) {
#pragma unroll
                for (int r = 0; r < 16; r++) mx = fmaxf(mx, st[1][r]);
            }
            float pm = fmaxf(mx, __shfl_xor(mx, 32));   // full 64-k row max

            if (__any(pm > m_run + 8.f)) {     // T13 defer-max
                float mnew = fmaxf(m_run, pm);
                float ps   = exp2f(m_run - mnew);
                m_run = mnew;
                lsum *= ps;
#pragma unroll
                for (int r = 0; r < 16; r++) {
                    float psr = __shfl(ps, (r & 3) + 8 * (r >> 2) + 4 * hi);
#pragma unroll
                    for (int dt = 0; dt < 4; dt++) o[dt][r] *= psr;
                }
            }
            float ls = 0.f;
#pragma unroll
            for (int r = 0; r < 16; r++) {
                float p = exp2f(st[0][r] - m_run);
                st[0][r] = p; ls += p;
            }
            if (act1) {
#pragma unroll
                for (int r = 0; r < 16; r++) {
                    float p = exp2f(st[1][r] - m_run);
                    st[1][r] = p; ls += p;
                }
            }
            lsum += ls + __shfl_xor(ls, 32);

            // ---- P->A-frags lane-local + O += P V ----
            // step ks: rows r = 8*(ks&1)+[0,8) of st[ks>>1];
            // element jj <-> k = 16ks + 8*(jj>>2) + 4hi + (jj&3)  (pairing g)
            const char* vbase = (const char*)&Vs[cur][0];
            __builtin_amdgcn_s_setprio(1);
#pragma unroll
            for (int ks = 0; ks < 4; ks++) {
                if (ks < 2 || act1) {
                    const f32x16& sv = st[ks >> 1];
                    const int g = (ks & 1) * 8;
                    unsigned int d0 = (unsigned)f2bf(sv[g + 0]) | ((unsigned)f2bf(sv[g + 1]) << 16);
                    unsigned int d1 = (unsigned)f2bf(sv[g + 2]) | ((unsigned)f2bf(sv[g + 3]) << 16);
                    unsigned int d2 = (unsigned)f2bf(sv[g + 4]) | ((unsigned)f2bf(sv[g + 5]) << 16);
                    unsigned int d3 = (unsigned)f2bf(sv[g + 6]) | ((unsigned)f2bf(sv[g + 7]) << 16);
                    u32x4 paw = {d0, d1, d2, d3};
                    bf16x8 pa = __builtin_bit_cast(bf16x8, paw);
#pragma unroll
                    for (int dt = 0; dt < 4; dt++) {
                        int d = dt * 32 + ln;
                        const char* vrow = vbase + d * 128;
                        int x = d & 7;
                        uint2 vlo = *(const uint2*)(vrow + (((2 * ks)     ^ x) * 16) + hi * 8);
                        uint2 vhi = *(const uint2*)(vrow + (((2 * ks + 1) ^ x) * 16) + hi * 8);
                        u32x4 vw = {vlo.x, vlo.y, vhi.x, vhi.y};
                        bf16x8 vf = __builtin_bit_cast(bf16x8, vw);
                        o[dt] = __builtin_amdgcn_mfma_f32_32x32x16_bf16(pa, vf, o[dt], 0, 0, 0);
                    }
                }
            }
            __builtin_amdgcn_s_setprio(0);
        }
    }

    // ---- epilogue: normalize, store f32 [B,S,H,D] ----
    float rcp = 1.0f / lsum;                   // owner lane ln holds q-row q0+ln
    float* ob = out + ((size_t)(b * S_LEN + q0) * NH + h) * D_DIM;
#pragma unroll
    for (int r = 0; r < 16; r++) {
        int qo = (r & 3) + 8 * (r >> 2) + 4 * hi;
        float invr = __shfl(rcp, qo);
#pragma unroll
        for (int dt = 0; dt < 4; dt++)
            ob[(size_t)qo * NH * D_DIM + dt * 32 + ln] = o[dt][r] * invr;
    }
}

extern "C" void kernel_launch(void* const* d_in, const int* in_sizes, int n_in,
                              void* d_out, int out_size, void* d_ws, size_t ws_size,
                              hipStream_t stream) {
    const float* q    = (const float*)d_in[0];
    const float* k    = (const float*)d_in[1];
    const float* v    = (const float*)d_in[2];
    const float* cosb = (const float*)d_in[3];
    const float* sinb = (const float*)d_in[4];
    // d_in[5] = attention_mask: exactly causal -> implemented analytically
    const float* scale = (const float*)d_in[6];
    float* out = (float*)d_out;

    unsigned short* Qr = (unsigned short*)d_ws;
    unsigned short* Kr = Qr + (size_t)NB * NH  * S_LEN * D_DIM;
    unsigned short* Vt = Kr + (size_t)NB * NKV * S_LEN * D_DIM;

    prep_kernel<<<20736, 256, 0, stream>>>(q, k, v, cosb, sinb, scale, Qr, Kr, Vt);
    attn_kernel<<<512, 256, 0, stream>>>(Qr, Kr, Vt, out);
}